// Round 18
// baseline (202.823 us; speedup 1.0000x reference)
//
#include <hip/hip_runtime.h>
#include <cstdint>
#include <cstddef>

// Problem constants (AltAttention: B=2, S=2048, D=1024, H=16, dh=64)
#define B_  2
#define S_  2048
#define D_  1024
#define H_  16
#define DH_ 64
#define M_  (B_*S_)     // 4096 rows
#define N3_ (3*D_)      // 3072 qkv cols
#define NTH_ 16         // key tiles per split-K half

typedef float f32x4 __attribute__((ext_vector_type(4)));
typedef short short8 __attribute__((ext_vector_type(8)));
typedef int   i32x4 __attribute__((ext_vector_type(4)));
typedef unsigned short u16x8 __attribute__((ext_vector_type(8)));
typedef unsigned short u16x4 __attribute__((ext_vector_type(4)));
typedef unsigned short u16x2 __attribute__((ext_vector_type(2)));

__device__ __forceinline__ unsigned short f2bf(float x) {
    unsigned int u = __float_as_uint(x);
    unsigned int r = (u + 0x7FFFu + ((u >> 16) & 1u)) >> 16;
    return (unsigned short)r;
}

__device__ __forceinline__ float exp2_(float x) { return __builtin_amdgcn_exp2f(x); }

__device__ __forceinline__ unsigned int cvt_pk_bf16(float a, float b) {
    unsigned int r;
    asm volatile("v_cvt_pk_bf16_f32 %0, %1, %2" : "=v"(r) : "v"(a), "v"(b));
    return r;
}

// LDS granule swizzle (verified r17): byte ^= s3(row)<<4.
__device__ __forceinline__ int s3x(int row) {
    return (((row & 3) | (((row >> 3) & 1) << 2)) << 4);
}

// XCD-chunked workgroup swizzle (bijective when nwg % 8 == 0). ATTENTION ONLY.
__device__ __forceinline__ int xcd_swizzle(int lin, int nwg) {
    const int cpx = nwg >> 3;
    return (lin & 7) * cpx + (lin >> 3);
}

__device__ __forceinline__ void gload16(const void* g, void* l) {
    __builtin_amdgcn_global_load_lds(
        (const __attribute__((address_space(1))) unsigned int*)g,
        (__attribute__((address_space(3))) unsigned int*)l,
        16, 0, 0);
}

// ---------------------------------------------------------------------------
// Merged mask detect + expand (verified r16/r17).
// ---------------------------------------------------------------------------
__global__ void k_mask(const unsigned char* __restrict__ mb, float* __restrict__ maskbias) {
    __shared__ int sBig, sM4, sM8;
    if (threadIdx.x == 0) { sBig = 0; sM4 = 0; sM8 = 0; }
    __syncthreads();
    int big = 0, m4 = 0, m8 = 0;
    for (int i = threadIdx.x; i < 4096; i += 256) {
        unsigned char v = mb[i];
        if (v > 1) big = 1;
        if (v && (i & 3)) m4 = 1;
        if (v && ((i & 7) == 4)) m8 = 1;
    }
    if (big) atomicOr(&sBig, 1);
    if (m4)  atomicOr(&sM4, 1);
    if (m8)  atomicOr(&sM8, 1);
    __syncthreads();
    const int w = sBig ? 0 : (sM4 ? 1 : (sM8 ? 4 : 8));
    const int i = blockIdx.x * 256 + threadIdx.x;
    bool on;
    if (w == 0)      on = ((const float*)mb)[i] != 0.0f;
    else if (w == 1) on = mb[i] != 0;
    else if (w == 4) on = ((const int*)mb)[i] != 0;
    else             on = ((const long long*)mb)[i] != 0;
    maskbias[i] = on ? 0.0f : -1e30f;
}

// ---------------------------------------------------------------------------
// Merged fp32 -> bf16 convert (verified r12-r17).
// ---------------------------------------------------------------------------
__global__ void k_f2bf3(const float* __restrict__ A, const float* __restrict__ B2,
                        const float* __restrict__ C, unsigned short* __restrict__ oA,
                        unsigned short* __restrict__ oB, unsigned short* __restrict__ oC) {
    const int nA = M_ * D_, nB = N3_ * D_, nC = D_ * D_;
    int i = (blockIdx.x * 256 + threadIdx.x) * 4;
    const float* src; unsigned short* dst; int off;
    if (i < nA)           { src = A;  dst = oA; off = i; }
    else if (i < nA + nB) { src = B2; dst = oB; off = i - nA; }
    else if (i < nA + nB + nC) { src = C; dst = oC; off = i - nA - nB; }
    else return;
    float4 v = *reinterpret_cast<const float4*>(&src[off]);
    u16x4 o = { f2bf(v.x), f2bf(v.y), f2bf(v.z), f2bf(v.w) };
    *reinterpret_cast<u16x4*>(&dst[off]) = o;
}

// ---------------------------------------------------------------------------
// bf16 MFMA GEMM, counted-vmcnt K-loop + XOR swizzle (verified r15/r17).
// ---------------------------------------------------------------------------
template <bool OUT_BF16>
__global__ __launch_bounds__(512) void k_gemm_bf16_cv(
    const unsigned short* __restrict__ A, const unsigned short* __restrict__ W,
    const float* __restrict__ bias, void* __restrict__ Cout,
    int M, int N, int K) {
    __shared__ __align__(16) unsigned short Al[3][128 * 64];
    __shared__ __align__(16) unsigned short Wl[3][128 * 64];

    const int tid  = threadIdx.x;
    const int lane = tid & 63;
    const int w    = tid >> 6;
    const int wr   = w >> 2, wc = w & 3;
    const int l16  = lane & 15, g = lane >> 4;
    const int m0 = blockIdx.y * 128, n0 = blockIdx.x * 128;
    const int NTk = K >> 6;

    f32x4 acc[4][2];
#pragma unroll
    for (int m = 0; m < 4; ++m)
#pragma unroll
        for (int n = 0; n < 2; ++n) acc[m][n] = (f32x4){0.f, 0.f, 0.f, 0.f};

    auto issueTile = [&](int kt) {
        const int k0 = kt << 6;
        unsigned short* Ad = Al[kt % 3];
        unsigned short* Wd = Wl[kt % 3];
#pragma unroll
        for (int i = 0; i < 2; ++i) {
            const int c = i * 512 + tid;
            const int row = c >> 3;
            const int colel = (((c & 7) ^ (row & 7)) << 3);
            gload16(A + (size_t)(m0 + row) * K + k0 + colel, Ad + c * 8);
            gload16(W + (size_t)(n0 + row) * K + k0 + colel, Wd + c * 8);
        }
    };

    issueTile(0);
    issueTile(1);

    for (int t = 0; t < NTk; ++t) {
        if (t + 2 < NTk) issueTile(t + 2);

        if (t < NTk - 2)       asm volatile("s_waitcnt vmcnt(8)" ::: "memory");
        else if (t == NTk - 2) asm volatile("s_waitcnt vmcnt(4)" ::: "memory");
        else                   asm volatile("s_waitcnt vmcnt(0)" ::: "memory");
        __builtin_amdgcn_s_barrier();
        __builtin_amdgcn_sched_barrier(0);

        const unsigned short* Ab = Al[t % 3];
        const unsigned short* Wb = Wl[t % 3];
        short8 a[4][2], b[2][2];
#pragma unroll
        for (int m = 0; m < 4; ++m)
#pragma unroll
            for (int kk = 0; kk < 2; ++kk) {
                const int row = wr * 64 + m * 16 + l16;
                const int kb = (kk * 64 + g * 16) ^ ((row & 7) << 4);
                a[m][kk] = *reinterpret_cast<const short8*>(
                    (const char*)Ab + row * 128 + kb);
            }
#pragma unroll
        for (int n = 0; n < 2; ++n)
#pragma unroll
            for (int kk = 0; kk < 2; ++kk) {
                const int row = wc * 32 + n * 16 + l16;
                const int kb = (kk * 64 + g * 16) ^ ((row & 7) << 4);
                b[n][kk] = *reinterpret_cast<const short8*>(
                    (const char*)Wb + row * 128 + kb);
            }

        __builtin_amdgcn_s_setprio(1);
#pragma unroll
        for (int kk = 0; kk < 2; ++kk)
#pragma unroll
            for (int m = 0; m < 4; ++m)
#pragma unroll
                for (int n = 0; n < 2; ++n)
                    acc[m][n] = __builtin_amdgcn_mfma_f32_16x16x32_bf16(
                        a[m][kk], b[n][kk], acc[m][n], 0, 0, 0);
        __builtin_amdgcn_s_setprio(0);

        __builtin_amdgcn_sched_barrier(0);
        __builtin_amdgcn_s_barrier();
    }

    float bv[2];
#pragma unroll
    for (int n = 0; n < 2; ++n) bv[n] = bias[n0 + wc * 32 + n * 16 + l16];
#pragma unroll
    for (int m = 0; m < 4; ++m) {
#pragma unroll
        for (int r = 0; r < 4; ++r) {
            const size_t row = m0 + wr * 64 + m * 16 + g * 4 + r;
#pragma unroll
            for (int n = 0; n < 2; ++n) {
                const int col = n0 + wc * 32 + n * 16 + l16;
                float v = acc[m][n][r] + bv[n];
                if (OUT_BF16)
                    ((unsigned short*)Cout)[row * N + col] = f2bf(v);
                else
                    ((float*)Cout)[row * N + col] = v;
            }
        }
    }
}

// ---------------------------------------------------------------------------
// Flash attention SPLIT-K(2): r17's verified loop (row-permuted QK^T,
// lane-local P-pack, s3-swizzled 128B rows, V 3-buf, ONE barrier/tile)
// applied to a 16-tile key half; emits unnormalized O_partial + per-head
// (m,l). Grid 1024 -> 3 blocks/CU (LDS 40960 x 3 = 122.9 KB).
// [r13's split-K failure was its 2-barrier V-2buf lockstep, not split-K.]
// ---------------------------------------------------------------------------
__global__ __launch_bounds__(512, 4) void k_attn_split(
    const unsigned short* __restrict__ qkv,
    const float* __restrict__ maskbias,
    unsigned short* __restrict__ Opart,
    float2* __restrict__ mlbuf) {
    __shared__ __align__(16) unsigned short Kt[2][64][64];
    __shared__ __align__(16) unsigned short Vt[3][64][64];

    const int tid  = threadIdx.x;
    const int lane = tid & 63;
    const int wq   = tid >> 6;           // wave 0..7 -> 16-row q-strip
    const int g    = lane >> 4;
    const int g4   = g * 4;
    const int l16  = lane & 15;

    const int nqt = S_ / 128;            // 16 q-tiles
    const int nwg = B_ * H_ * nqt * 2;   // 1024 (%8 == 0)
    const int lin = xcd_swizzle(blockIdx.x, nwg);
    const int half = lin & 1;
    const int bhq  = lin >> 1;
    const int qt = bhq % nqt;
    const int h  = (bhq / nqt) % H_;
    const int b  = bhq / (nqt * H_);
    const int q0 = qt * 128;
    const int kb0 = half * (NTH_ * 64);  // absolute base key of this half
    const size_t rowbase = (size_t)b * S_ * N3_;
    const int hq = h * 192, hk = hq + 64, hv = hq + 128;
    const unsigned short* kvb = qkv + rowbase;
    const float* mbp = maskbias + b * S_;

    // permuted fragment-row base for QK^T A-operand (K rows)
    const int blrow = 8 * (l16 >> 2) + (l16 & 3);
    const int KBJ[4] = { 0, 4, 32, 36 };

    // ---- Q fragments directly from global (one-time)
    const unsigned short* qrp = kvb + (size_t)(q0 + wq * 16 + l16) * N3_ + hq;
    const short8 qa0 = *reinterpret_cast<const short8*>(qrp + g * 8);
    const short8 qa1 = *reinterpret_cast<const short8*>(qrp + 32 + g * 8);

    // staging geometry
    const int krow = tid >> 3;                         // 0..63
    const int kgr  = tid & 7;                          // K: 16B granule
    const int vkb4 = (tid & 31) * 4;                   // V: byte col (4 B)
    const int vdb  = (tid >> 5) * 4;                   // V: dim base
    u16x8 kr;
    u16x4 vr0, vr1;

    const int kwOff = (kgr << 4) ^ s3x(krow);

    // ---- prologue: stage tile kb0 -> K[0],V[0]
    {
        kr  = *reinterpret_cast<const u16x8*>(kvb + (size_t)(kb0 + krow) * N3_ + hk + kgr * 8);
        const unsigned short* vs = kvb + (size_t)(kb0 + (tid & 31) * 2) * N3_ + hv + vdb;
        vr0 = *reinterpret_cast<const u16x4*>(vs);
        vr1 = *reinterpret_cast<const u16x4*>(vs + N3_);
        *reinterpret_cast<u16x8*>((char*)&Kt[0][krow][0] + kwOff) = kr;
#pragma unroll
        for (int j = 0; j < 4; ++j)
            *reinterpret_cast<u16x2*>((char*)&Vt[0][vdb + j][0] + (vkb4 ^ s3x(vdb + j))) =
                (u16x2){vr0[j], vr1[j]};
    }
    __syncthreads();

    f32x4 Oacc[4];
#pragma unroll
    for (int df = 0; df < 4; ++df) Oacc[df] = (f32x4){0.f, 0.f, 0.f, 0.f};
    float m = -1e30f, l = 0.0f;

    const float LOG2E = 1.4426950408889634f;
    const float c1 = 0.03125f * LOG2E;                       // scale * log2e
    const float c2 = exp2f(-0.5f * (float)(h + 1)) * LOG2E;  // slope * log2e
    const int   qw0 = q0 + wq * 16;
    const int   qg  = qw0 + l16;
    const float alg = c2 * (float)(8 * g);
    float albr[4];
#pragma unroll
    for (int r = 0; r < 4; ++r) albr[r] = c2 * (float)r;
    const float ckb[4] = { 0.0f, c2 * 4.0f, c2 * 32.0f, c2 * 36.0f };

    const int sK = s3x(blrow);
    const int kr0Off = (g << 4) ^ sK;
    const int kr1Off = ((4 + g) << 4) ^ sK;
    const int sV = s3x(l16);
    const int vr0Off = (g << 4) ^ sV;
    const int vr1Off = ((4 + g) << 4) ^ sV;

    float p_[4][4];

    // ---- prologue continued: issue tile kb0+64 loads, QK^T(tile 0), write tile 1
    {
        kr  = *reinterpret_cast<const u16x8*>(kvb + (size_t)(kb0 + 64 + krow) * N3_ + hk + kgr * 8);
        const unsigned short* vs = kvb + (size_t)(kb0 + 64 + (tid & 31) * 2) * N3_ + hv + vdb;
        vr0 = *reinterpret_cast<const u16x4*>(vs);
        vr1 = *reinterpret_cast<const u16x4*>(vs + N3_);

        __builtin_amdgcn_s_setprio(1);
#pragma unroll
        for (int jb = 0; jb < 4; ++jb) {
            const char* rowp = (const char*)&Kt[0][blrow + KBJ[jb]][0];
            short8 kb0_ = *reinterpret_cast<const short8*>(rowp + kr0Off);
            short8 kb1_ = *reinterpret_cast<const short8*>(rowp + kr1Off);
            f32x4 c = (f32x4){0.f, 0.f, 0.f, 0.f};
            c = __builtin_amdgcn_mfma_f32_16x16x32_bf16(kb0_, qa0, c, 0, 0, 0);
            c = __builtin_amdgcn_mfma_f32_16x16x32_bf16(kb1_, qa1, c, 0, 0, 0);
#pragma unroll
            for (int r = 0; r < 4; ++r) p_[jb][r] = c[r];
        }
        __builtin_amdgcn_s_setprio(0);

        *reinterpret_cast<u16x8*>((char*)&Kt[1][krow][0] + kwOff) = kr;
#pragma unroll
        for (int j = 0; j < 4; ++j)
            *reinterpret_cast<u16x2*>((char*)&Vt[1][vdb + j][0] + (vkb4 ^ s3x(vdb + j))) =
                (u16x2){vr0[j], vr1[j]};
    }
    __syncthreads();
    // issue tile kb0+128 loads
    {
        kr  = *reinterpret_cast<const u16x8*>(kvb + (size_t)(kb0 + 128 + krow) * N3_ + hk + kgr * 8);
        const unsigned short* vs = kvb + (size_t)(kb0 + 128 + (tid & 31) * 2) * N3_ + hv + vdb;
        vr0 = *reinterpret_cast<const u16x4*>(vs);
        vr1 = *reinterpret_cast<const u16x4*>(vs + N3_);
    }

    int vb_r = 0;
    int vb_w = 2;

    for (int t = 1; t < NTH_ + 1; ++t) {
        const int k0m = kb0 + (t - 1) * 64;   // absolute key base of compute tile

        // ---- mask bias (keys k0m + 8g + KBJ[jb] + r)
        f32x4 amv[4];
#pragma unroll
        for (int jb = 0; jb < 4; ++jb)
            amv[jb] = *reinterpret_cast<const f32x4*>(&mbp[k0m + 8 * g + KBJ[jb]]);

        // ---- QK^T(t): issue FIRST, consumed next iteration
        f32x4 cnx[4];
        if (t < NTH_) {
            const unsigned short (*Kc)[64] = Kt[t & 1];
            __builtin_amdgcn_s_setprio(1);
#pragma unroll
            for (int jb = 0; jb < 4; ++jb) {
                const char* rowp = (const char*)&Kc[blrow + KBJ[jb]][0];
                short8 kf0 = *reinterpret_cast<const short8*>(rowp + kr0Off);
                short8 kf1 = *reinterpret_cast<const short8*>(rowp + kr1Off);
                f32x4 c = (f32x4){0.f, 0.f, 0.f, 0.f};
                c = __builtin_amdgcn_mfma_f32_16x16x32_bf16(kf0, qa0, c, 0, 0, 0);
                c = __builtin_amdgcn_mfma_f32_16x16x32_bf16(kf1, qa1, c, 0, 0, 0);
                cnx[jb] = c;
            }
            __builtin_amdgcn_s_setprio(0);
        }

        // ---- scores of compute tile (key = k0m + 8g + KBJ[jb] + r)
        if (k0m + 64 <= qw0) {
            const float tbg = c2 * (float)(k0m - qg) + alg;
#pragma unroll
            for (int jb = 0; jb < 4; ++jb) {
                const float tbj = tbg + ckb[jb];
#pragma unroll
                for (int r = 0; r < 4; ++r)
                    p_[jb][r] = fmaf(p_[jb][r], c1, tbj + albr[r] + amv[jb][r]);
            }
        } else if (k0m >= qw0 + 16) {
            const float tbg = c2 * (float)(k0m - qg) + alg;
#pragma unroll
            for (int jb = 0; jb < 4; ++jb) {
                const float tbj = -tbg - ckb[jb];
#pragma unroll
                for (int r = 0; r < 4; ++r)
                    p_[jb][r] = fmaf(p_[jb][r], c1, tbj - albr[r] + amv[jb][r]);
            }
        } else {
            const int dbase = k0m - qg + 8 * g;
#pragma unroll
            for (int jb = 0; jb < 4; ++jb)
#pragma unroll
                for (int r = 0; r < 4; ++r) {
                    int d = dbase + KBJ[jb] + r;
                    d = d < 0 ? -d : d;
                    p_[jb][r] = fmaf(p_[jb][r], c1, amv[jb][r] - c2 * (float)d);
                }
        }

        // ---- row max
        float mx;
        {
            float m0_ = fmaxf(fmaxf(p_[0][0], p_[0][1]), fmaxf(p_[0][2], p_[0][3]));
            float m1_ = fmaxf(fmaxf(p_[1][0], p_[1][1]), fmaxf(p_[1][2], p_[1][3]));
            float m2_ = fmaxf(fmaxf(p_[2][0], p_[2][1]), fmaxf(p_[2][2], p_[2][3]));
            float m3_ = fmaxf(fmaxf(p_[3][0], p_[3][1]), fmaxf(p_[3][2], p_[3][3]));
            mx = fmaxf(fmaxf(m0_, m1_), fmaxf(m2_, m3_));
        }
        mx = fmaxf(mx, __shfl_xor(mx, 16));
        mx = fmaxf(mx, __shfl_xor(mx, 32));

        // ---- defer-max rescale (rare)
        if (__any(mx > m + 8.0f)) {
            const float mn = fmaxf(m, mx);
            const float cr = exp2_(m - mn);
            m = mn;
            l *= cr;
            const int srcb = (lane & 48) + ((lane & 48) >> 2);
#pragma unroll
            for (int r = 0; r < 4; ++r) {
                const float crq = __shfl(cr, srcb + r);
#pragma unroll
                for (int df = 0; df < 4; ++df) Oacc[df][r] *= crq;
            }
        }

        // ---- exp + local sum
        float ps = 0.0f;
#pragma unroll
        for (int jb = 0; jb < 4; ++jb)
#pragma unroll
            for (int r = 0; r < 4; ++r) {
                float p = exp2_(p_[jb][r] - m);
                p_[jb][r] = p;
                ps += p;
            }

        // ---- P-pack: LANE-LOCAL
        short8 pa0, pa1;
        {
            i32x4 w0 = { (int)cvt_pk_bf16(p_[0][0], p_[0][1]),
                         (int)cvt_pk_bf16(p_[0][2], p_[0][3]),
                         (int)cvt_pk_bf16(p_[1][0], p_[1][1]),
                         (int)cvt_pk_bf16(p_[1][2], p_[1][3]) };
            i32x4 w1 = { (int)cvt_pk_bf16(p_[2][0], p_[2][1]),
                         (int)cvt_pk_bf16(p_[2][2], p_[2][3]),
                         (int)cvt_pk_bf16(p_[3][0], p_[3][1]),
                         (int)cvt_pk_bf16(p_[3][2], p_[3][3]) };
            pa0 = __builtin_bit_cast(short8, w0);
            pa1 = __builtin_bit_cast(short8, w1);
        }

        // ---- PV: A = P (in-register), B = Vt[vb_r]
        {
            const unsigned short (*Vc)[64] = Vt[vb_r];
            __builtin_amdgcn_s_setprio(1);
#pragma unroll
            for (int df = 0; df < 4; ++df) {
                const char* rowp = (const char*)&Vc[df * 16 + l16][0];
                short8 vb0 = *reinterpret_cast<const short8*>(rowp + vr0Off);
                short8 vb1 = *reinterpret_cast<const short8*>(rowp + vr1Off);
                Oacc[df] = __builtin_amdgcn_mfma_f32_16x16x32_bf16(pa0, vb0, Oacc[df], 0, 0, 0);
                Oacc[df] = __builtin_amdgcn_mfma_f32_16x16x32_bf16(pa1, vb1, Oacc[df], 0, 0, 0);
            }
            __builtin_amdgcn_s_setprio(0);
        }

        // ---- deferred l update
        ps += __shfl_xor(ps, 16);
        ps += __shfl_xor(ps, 32);
        l += ps;

        // ---- stage tile t+1 into LDS, ONE barrier
        if (t + 1 < NTH_) {
            *reinterpret_cast<u16x8*>((char*)&Kt[(t + 1) & 1][krow][0] + kwOff) = kr;
#pragma unroll
            for (int j = 0; j < 4; ++j)
                *reinterpret_cast<u16x2*>((char*)&Vt[vb_w][vdb + j][0] + (vkb4 ^ s3x(vdb + j))) =
                    (u16x2){vr0[j], vr1[j]};
            __syncthreads();
            if (t + 2 < NTH_) {
                const int kn = kb0 + (t + 2) * 64;
                kr  = *reinterpret_cast<const u16x8*>(kvb + (size_t)(kn + krow) * N3_ + hk + kgr * 8);
                const unsigned short* vs = kvb + (size_t)(kn + (tid & 31) * 2) * N3_ + hv + vdb;
                vr0 = *reinterpret_cast<const u16x4*>(vs);
                vr1 = *reinterpret_cast<const u16x4*>(vs + N3_);
            }
        }
        vb_r = (vb_r == 2) ? 0 : vb_r + 1;
        vb_w = (vb_w == 2) ? 0 : vb_w + 1;

        if (t < NTH_) {
#pragma unroll
            for (int jb = 0; jb < 4; ++jb)
#pragma unroll
                for (int r = 0; r < 4; ++r) p_[jb][r] = cnx[jb][r];
        }
    }

    // ---- store unnormalized partial O + per-head (m, l)
    unsigned short* Ob = Opart + (size_t)half * M_ * D_;
#pragma unroll
    for (int df = 0; df < 4; ++df) {
#pragma unroll
        for (int r = 0; r < 4; ++r) {
            const int qrow = q0 + wq * 16 + g4 + r;
            Ob[(size_t)(b * S_ + qrow) * D_ + h * 64 + df * 16 + l16] = f2bf(Oacc[df][r]);
        }
    }
    if (g == 0)
        mlbuf[((size_t)half * M_ + b * S_ + qw0 + l16) * H_ + h] = make_float2(m, l);
}

// ---------------------------------------------------------------------------
// Combine the two split-K halves per head (verified r13): h = col>>6.
// ---------------------------------------------------------------------------
__global__ __launch_bounds__(256) void k_attn_combine(
    const unsigned short* __restrict__ Op, const float2* __restrict__ ml,
    unsigned short* __restrict__ xb) {
    const int idx = blockIdx.x * 256 + threadIdx.x;
    const int row = idx >> 7;              // 128 threads per 1024-col row
    const int col = (idx & 127) * 8;
    const int h   = col >> 6;
    const float2 a = ml[(size_t)row * H_ + h];
    const float2 c = ml[((size_t)M_ + row) * H_ + h];
    const float ms = fmaxf(a.x, c.x);
    const float e0 = exp2_(a.x - ms), e1 = exp2_(c.x - ms);
    const float inv = 1.0f / fmaf(a.y, e0, c.y * e1);
    const float s0 = e0 * inv, s1 = e1 * inv;
    const u16x8 v0 = *reinterpret_cast<const u16x8*>(&Op[(size_t)row * D_ + col]);
    const u16x8 v1 = *reinterpret_cast<const u16x8*>(&Op[((size_t)M_ + row) * D_ + col]);
    u16x8 o;
#pragma unroll
    for (int j = 0; j < 8; ++j) {
        float f0 = __uint_as_float((unsigned int)v0[j] << 16);
        float f1 = __uint_as_float((unsigned int)v1[j] << 16);
        o[j] = f2bf(fmaf(f0, s0, f1 * s1));
    }
    *reinterpret_cast<u16x8*>(&xb[(size_t)row * D_ + col]) = o;
}

// ---------------------------------------------------------------------------
extern "C" void kernel_launch(void* const* d_in, const int* in_sizes, int n_in,
                              void* d_out, int out_size, void* d_ws, size_t ws_size,
                              hipStream_t stream) {
    const float* inputs = (const float*)d_in[0];
    const void*  mask   = d_in[1];
    const float* Wqkv   = (const float*)d_in[2];
    const float* bqkv   = (const float*)d_in[3];
    const float* Wproj  = (const float*)d_in[4];
    const float* bproj  = (const float*)d_in[5];
    float* out = (float*)d_out;

    // workspace layout
    unsigned short* qkvb  = (unsigned short*)d_ws;          // M*N3 bf16
    unsigned short* xb    = qkvb + (size_t)M_ * N3_;        // M*D  bf16
    unsigned short* Ab    = xb + (size_t)M_ * D_;           // M*D  bf16 (inputs)
    unsigned short* Wqb   = Ab + (size_t)M_ * D_;           // N3*D bf16
    unsigned short* Wpb   = Wqb + (size_t)N3_ * D_;         // D*D  bf16
    unsigned short* Opart = Wpb + (size_t)D_ * D_;          // 2*M*D bf16
    float*  maskbias = (float*)(Opart + (size_t)2 * M_ * D_);  // M floats
    float2* mlbuf    = (float2*)(maskbias + M_);            // 2*M*H float2

    k_mask<<<M_ / 256, 256, 0, stream>>>((const unsigned char*)mask, maskbias);

    const int ntot = M_ * D_ + N3_ * D_ + D_ * D_;
    k_f2bf3<<<(ntot / 4 + 255) / 256, 256, 0, stream>>>(inputs, Wqkv, Wproj, Ab, Wqb, Wpb);

    dim3 g1(N3_ / 128, M_ / 128);   // 24 x 32
    k_gemm_bf16_cv<true><<<g1, 512, 0, stream>>>(Ab, Wqb, bqkv, qkvb, M_, N3_, D_);

    k_attn_split<<<B_ * H_ * (S_ / 128) * 2, 512, 0, stream>>>(qkvb, maskbias, Opart, mlbuf);
    k_attn_combine<<<M_ * D_ / 8 / 256, 256, 0, stream>>>(Opart, mlbuf, xb);

    dim3 g2(D_ / 128, M_ / 128);    // 8 x 32
    k_gemm_bf16_cv<false><<<g2, 512, 0, stream>>>(xb, Wpb, bproj, out, M_, D_, D_);
}

// Round 19
// 165.238 us; speedup vs baseline: 1.2275x; 1.2275x over previous
//
#include <hip/hip_runtime.h>
#include <cstdint>
#include <cstddef>

// Problem constants (AltAttention: B=2, S=2048, D=1024, H=16, dh=64)
#define B_  2
#define S_  2048
#define D_  1024
#define H_  16
#define DH_ 64
#define M_  (B_*S_)     // 4096 rows
#define N3_ (3*D_)      // 3072 qkv cols
#define NT_ (S_/64)     // 32 key tiles

typedef float f32x4 __attribute__((ext_vector_type(4)));
typedef short short8 __attribute__((ext_vector_type(8)));
typedef int   i32x4 __attribute__((ext_vector_type(4)));
typedef unsigned short u16x8 __attribute__((ext_vector_type(8)));
typedef unsigned short u16x4 __attribute__((ext_vector_type(4)));
typedef unsigned short u16x2 __attribute__((ext_vector_type(2)));

__device__ __forceinline__ unsigned short f2bf(float x) {
    unsigned int u = __float_as_uint(x);
    unsigned int r = (u + 0x7FFFu + ((u >> 16) & 1u)) >> 16;
    return (unsigned short)r;
}

__device__ __forceinline__ float exp2_(float x) { return __builtin_amdgcn_exp2f(x); }

__device__ __forceinline__ unsigned int cvt_pk_bf16(float a, float b) {
    unsigned int r;
    asm volatile("v_cvt_pk_bf16_f32 %0, %1, %2" : "=v"(r) : "v"(a), "v"(b));
    return r;
}

// LDS granule swizzle for attn K/V tiles (128-byte rows, 16B granules):
// byte ^= s3(row)<<4 with s3 = (row&3) | (((row>>3)&1)<<2). (verified r17)
__device__ __forceinline__ int s3x(int row) {
    return (((row & 3) | (((row >> 3) & 1) << 2)) << 4);
}

// XCD-chunked workgroup swizzle (bijective when nwg % 8 == 0). ATTENTION ONLY.
__device__ __forceinline__ int xcd_swizzle(int lin, int nwg) {
    const int cpx = nwg >> 3;
    return (lin & 7) * cpx + (lin >> 3);
}

__device__ __forceinline__ void gload16(const void* g, void* l) {
    __builtin_amdgcn_global_load_lds(
        (const __attribute__((address_space(1))) unsigned int*)g,
        (__attribute__((address_space(3))) unsigned int*)l,
        16, 0, 0);
}

// ---------------------------------------------------------------------------
// Merged mask detect + expand (verified r16/r17).
// ---------------------------------------------------------------------------
__global__ void k_mask(const unsigned char* __restrict__ mb, float* __restrict__ maskbias) {
    __shared__ int sBig, sM4, sM8;
    if (threadIdx.x == 0) { sBig = 0; sM4 = 0; sM8 = 0; }
    __syncthreads();
    int big = 0, m4 = 0, m8 = 0;
    for (int i = threadIdx.x; i < 4096; i += 256) {
        unsigned char v = mb[i];
        if (v > 1) big = 1;
        if (v && (i & 3)) m4 = 1;
        if (v && ((i & 7) == 4)) m8 = 1;
    }
    if (big) atomicOr(&sBig, 1);
    if (m4)  atomicOr(&sM4, 1);
    if (m8)  atomicOr(&sM8, 1);
    __syncthreads();
    const int w = sBig ? 0 : (sM4 ? 1 : (sM8 ? 4 : 8));
    const int i = blockIdx.x * 256 + threadIdx.x;
    bool on;
    if (w == 0)      on = ((const float*)mb)[i] != 0.0f;
    else if (w == 1) on = mb[i] != 0;
    else if (w == 4) on = ((const int*)mb)[i] != 0;
    else             on = ((const long long*)mb)[i] != 0;
    maskbias[i] = on ? 0.0f : -1e30f;
}

// ---------------------------------------------------------------------------
// Merged fp32 -> bf16 convert (verified r12-r17).
// ---------------------------------------------------------------------------
__global__ void k_f2bf3(const float* __restrict__ A, const float* __restrict__ B2,
                        const float* __restrict__ C, unsigned short* __restrict__ oA,
                        unsigned short* __restrict__ oB, unsigned short* __restrict__ oC) {
    const int nA = M_ * D_, nB = N3_ * D_, nC = D_ * D_;
    int i = (blockIdx.x * 256 + threadIdx.x) * 4;
    const float* src; unsigned short* dst; int off;
    if (i < nA)           { src = A;  dst = oA; off = i; }
    else if (i < nA + nB) { src = B2; dst = oB; off = i - nA; }
    else if (i < nA + nB + nC) { src = C; dst = oC; off = i - nA - nB; }
    else return;
    float4 v = *reinterpret_cast<const float4*>(&src[off]);
    u16x4 o = { f2bf(v.x), f2bf(v.y), f2bf(v.z), f2bf(v.w) };
    *reinterpret_cast<u16x4*>(&dst[off]) = o;
}

// ---------------------------------------------------------------------------
// bf16 MFMA GEMM, counted-vmcnt K-loop + XOR swizzle (verified r15/r17).
// ---------------------------------------------------------------------------
template <bool OUT_BF16>
__global__ __launch_bounds__(512) void k_gemm_bf16_cv(
    const unsigned short* __restrict__ A, const unsigned short* __restrict__ W,
    const float* __restrict__ bias, void* __restrict__ Cout,
    int M, int N, int K) {
    __shared__ __align__(16) unsigned short Al[3][128 * 64];
    __shared__ __align__(16) unsigned short Wl[3][128 * 64];

    const int tid  = threadIdx.x;
    const int lane = tid & 63;
    const int w    = tid >> 6;
    const int wr   = w >> 2, wc = w & 3;
    const int l16  = lane & 15, g = lane >> 4;
    const int m0 = blockIdx.y * 128, n0 = blockIdx.x * 128;
    const int NTk = K >> 6;

    f32x4 acc[4][2];
#pragma unroll
    for (int m = 0; m < 4; ++m)
#pragma unroll
        for (int n = 0; n < 2; ++n) acc[m][n] = (f32x4){0.f, 0.f, 0.f, 0.f};

    auto issueTile = [&](int kt) {
        const int k0 = kt << 6;
        unsigned short* Ad = Al[kt % 3];
        unsigned short* Wd = Wl[kt % 3];
#pragma unroll
        for (int i = 0; i < 2; ++i) {
            const int c = i * 512 + tid;
            const int row = c >> 3;
            const int colel = (((c & 7) ^ (row & 7)) << 3);
            gload16(A + (size_t)(m0 + row) * K + k0 + colel, Ad + c * 8);
            gload16(W + (size_t)(n0 + row) * K + k0 + colel, Wd + c * 8);
        }
    };

    issueTile(0);
    issueTile(1);

    for (int t = 0; t < NTk; ++t) {
        if (t + 2 < NTk) issueTile(t + 2);

        if (t < NTk - 2)       asm volatile("s_waitcnt vmcnt(8)" ::: "memory");
        else if (t == NTk - 2) asm volatile("s_waitcnt vmcnt(4)" ::: "memory");
        else                   asm volatile("s_waitcnt vmcnt(0)" ::: "memory");
        __builtin_amdgcn_s_barrier();
        __builtin_amdgcn_sched_barrier(0);

        const unsigned short* Ab = Al[t % 3];
        const unsigned short* Wb = Wl[t % 3];
        short8 a[4][2], b[2][2];
#pragma unroll
        for (int m = 0; m < 4; ++m)
#pragma unroll
            for (int kk = 0; kk < 2; ++kk) {
                const int row = wr * 64 + m * 16 + l16;
                const int kb = (kk * 64 + g * 16) ^ ((row & 7) << 4);
                a[m][kk] = *reinterpret_cast<const short8*>(
                    (const char*)Ab + row * 128 + kb);
            }
#pragma unroll
        for (int n = 0; n < 2; ++n)
#pragma unroll
            for (int kk = 0; kk < 2; ++kk) {
                const int row = wc * 32 + n * 16 + l16;
                const int kb = (kk * 64 + g * 16) ^ ((row & 7) << 4);
                b[n][kk] = *reinterpret_cast<const short8*>(
                    (const char*)Wb + row * 128 + kb);
            }

        __builtin_amdgcn_s_setprio(1);
#pragma unroll
        for (int kk = 0; kk < 2; ++kk)
#pragma unroll
            for (int m = 0; m < 4; ++m)
#pragma unroll
                for (int n = 0; n < 2; ++n)
                    acc[m][n] = __builtin_amdgcn_mfma_f32_16x16x32_bf16(
                        a[m][kk], b[n][kk], acc[m][n], 0, 0, 0);
        __builtin_amdgcn_s_setprio(0);

        __builtin_amdgcn_sched_barrier(0);
        __builtin_amdgcn_s_barrier();
    }

    float bv[2];
#pragma unroll
    for (int n = 0; n < 2; ++n) bv[n] = bias[n0 + wc * 32 + n * 16 + l16];
#pragma unroll
    for (int m = 0; m < 4; ++m) {
#pragma unroll
        for (int r = 0; r < 4; ++r) {
            const size_t row = m0 + wr * 64 + m * 16 + g * 4 + r;
#pragma unroll
            for (int n = 0; n < 2; ++n) {
                const int col = n0 + wc * 32 + n * 16 + l16;
                float v = acc[m][n][r] + bv[n];
                if (OUT_BF16)
                    ((unsigned short*)Cout)[row * N + col] = f2bf(v);
                else
                    ((float*)Cout)[row * N + col] = v;
            }
        }
    }
}

// ---------------------------------------------------------------------------
// Flash attention, swapped-QK^T, bf16 MFMA, tile-pipelined (r10 schedule)
// + row-permuted QK^T (lane-local P-pack, no LDS round trip) + s3 swizzle.
// Verified r17: 88 us steady-state, bank conflicts 0, LDS 40960.
// ---------------------------------------------------------------------------
__global__ __launch_bounds__(512, 4) void k_attn_mfma(
    const unsigned short* __restrict__ qkv,
    const float* __restrict__ maskbias,
    unsigned short* __restrict__ x) {
    __shared__ __align__(16) unsigned short Kt[2][64][64];
    __shared__ __align__(16) unsigned short Vt[3][64][64];

    const int tid  = threadIdx.x;
    const int lane = tid & 63;
    const int wq   = tid >> 6;           // wave 0..7 -> 16-row q-strip
    const int g    = lane >> 4;
    const int g4   = g * 4;
    const int l16  = lane & 15;

    const int nqt = S_ / 128;            // 16 q-tiles
    const int nwg = B_ * H_ * nqt;       // 512 (%8 == 0)
    const int bid = xcd_swizzle(blockIdx.x, nwg);
    const int qt = bid % nqt;
    const int h  = (bid / nqt) % H_;
    const int b  = bid / (nqt * H_);
    const int q0 = qt * 128;
    const size_t rowbase = (size_t)b * S_ * N3_;
    const int hq = h * 192, hk = hq + 64, hv = hq + 128;
    const unsigned short* kvb = qkv + rowbase;
    const float* mbp = maskbias + b * S_;

    // permuted fragment-row base for QK^T A-operand (K rows)
    const int blrow = 8 * (l16 >> 2) + (l16 & 3);
    const int KBJ[4] = { 0, 4, 32, 36 };

    // ---- Q fragments directly from global (one-time)
    const unsigned short* qrp = kvb + (size_t)(q0 + wq * 16 + l16) * N3_ + hq;
    const short8 qa0 = *reinterpret_cast<const short8*>(qrp + g * 8);
    const short8 qa1 = *reinterpret_cast<const short8*>(qrp + 32 + g * 8);

    // staging geometry
    const int krow = tid >> 3;                         // 0..63
    const int kgr  = tid & 7;                          // K: 16B granule
    const int vkb4 = (tid & 31) * 4;                   // V: byte col (4 B)
    const int vdb  = (tid >> 5) * 4;                   // V: dim base
    u16x8 kr;
    u16x4 vr0, vr1;

    const int kwOff = (kgr << 4) ^ s3x(krow);          // K write offset in row

    // ---- prologue: stage tile 0 -> K[0],V[0]
    {
        kr  = *reinterpret_cast<const u16x8*>(kvb + (size_t)krow * N3_ + hk + kgr * 8);
        const unsigned short* vs = kvb + (size_t)((tid & 31) * 2) * N3_ + hv + vdb;
        vr0 = *reinterpret_cast<const u16x4*>(vs);
        vr1 = *reinterpret_cast<const u16x4*>(vs + N3_);
        *reinterpret_cast<u16x8*>((char*)&Kt[0][krow][0] + kwOff) = kr;
#pragma unroll
        for (int j = 0; j < 4; ++j)
            *reinterpret_cast<u16x2*>((char*)&Vt[0][vdb + j][0] + (vkb4 ^ s3x(vdb + j))) =
                (u16x2){vr0[j], vr1[j]};
    }
    __syncthreads();

    f32x4 Oacc[4];
#pragma unroll
    for (int df = 0; df < 4; ++df) Oacc[df] = (f32x4){0.f, 0.f, 0.f, 0.f};
    float m = -1e30f, l = 0.0f;

    const float LOG2E = 1.4426950408889634f;
    const float c1 = 0.03125f * LOG2E;                       // scale * log2e
    const float c2 = exp2f(-0.5f * (float)(h + 1)) * LOG2E;  // slope * log2e
    const int   qw0 = q0 + wq * 16;
    const int   qg  = qw0 + l16;
    const float alg = c2 * (float)(8 * g);
    float albr[4];
#pragma unroll
    for (int r = 0; r < 4; ++r) albr[r] = c2 * (float)r;
    const float ckb[4] = { 0.0f, c2 * 4.0f, c2 * 32.0f, c2 * 36.0f };

    // per-lane swizzled read offsets
    const int sK = s3x(blrow);                         // same for all KBJ offsets
    const int kr0Off = (g << 4) ^ sK;
    const int kr1Off = ((4 + g) << 4) ^ sK;
    const int sV = s3x(l16);                           // df*16 doesn't affect s3
    const int vr0Off = (g << 4) ^ sV;
    const int vr1Off = ((4 + g) << 4) ^ sV;

    // score state of tile t-1
    float p_[4][4];

    // ---- prologue continued: issue tile-1 loads, QK^T(0), write tile 1
    {
        kr  = *reinterpret_cast<const u16x8*>(kvb + (size_t)(64 + krow) * N3_ + hk + kgr * 8);
        const unsigned short* vs = kvb + (size_t)(64 + (tid & 31) * 2) * N3_ + hv + vdb;
        vr0 = *reinterpret_cast<const u16x4*>(vs);
        vr1 = *reinterpret_cast<const u16x4*>(vs + N3_);

        __builtin_amdgcn_s_setprio(1);
#pragma unroll
        for (int jb = 0; jb < 4; ++jb) {
            const char* rowp = (const char*)&Kt[0][blrow + KBJ[jb]][0];
            short8 kb0 = *reinterpret_cast<const short8*>(rowp + kr0Off);
            short8 kb1 = *reinterpret_cast<const short8*>(rowp + kr1Off);
            f32x4 c = (f32x4){0.f, 0.f, 0.f, 0.f};
            c = __builtin_amdgcn_mfma_f32_16x16x32_bf16(kb0, qa0, c, 0, 0, 0);
            c = __builtin_amdgcn_mfma_f32_16x16x32_bf16(kb1, qa1, c, 0, 0, 0);
#pragma unroll
            for (int r = 0; r < 4; ++r) p_[jb][r] = c[r];
        }
        __builtin_amdgcn_s_setprio(0);

        *reinterpret_cast<u16x8*>((char*)&Kt[1][krow][0] + kwOff) = kr;
#pragma unroll
        for (int j = 0; j < 4; ++j)
            *reinterpret_cast<u16x2*>((char*)&Vt[1][vdb + j][0] + (vkb4 ^ s3x(vdb + j))) =
                (u16x2){vr0[j], vr1[j]};
    }
    __syncthreads();
    // issue tile-2 loads
    {
        kr  = *reinterpret_cast<const u16x8*>(kvb + (size_t)(128 + krow) * N3_ + hk + kgr * 8);
        const unsigned short* vs = kvb + (size_t)(128 + (tid & 31) * 2) * N3_ + hv + vdb;
        vr0 = *reinterpret_cast<const u16x4*>(vs);
        vr1 = *reinterpret_cast<const u16x4*>(vs + N3_);
    }

    int vb_r = 0;   // (t-1)%3 at loop entry t=1
    int vb_w = 2;   // (t+1)%3 at loop entry t=1

    for (int t = 1; t < NT_ + 1; ++t) {
        const int k0m = (t - 1) * 64;

        // ---- mask bias for tile t-1 (keys 8g+KBJ[jb]+r)
        f32x4 amv[4];
#pragma unroll
        for (int jb = 0; jb < 4; ++jb)
            amv[jb] = *reinterpret_cast<const f32x4*>(&mbp[k0m + 8 * g + KBJ[jb]]);

        // ---- QK^T(t): issue FIRST, consumed next iteration
        f32x4 cnx[4];
        if (t < NT_) {
            const unsigned short (*Kc)[64] = Kt[t & 1];
            __builtin_amdgcn_s_setprio(1);
#pragma unroll
            for (int jb = 0; jb < 4; ++jb) {
                const char* rowp = (const char*)&Kc[blrow + KBJ[jb]][0];
                short8 kb0 = *reinterpret_cast<const short8*>(rowp + kr0Off);
                short8 kb1 = *reinterpret_cast<const short8*>(rowp + kr1Off);
                f32x4 c = (f32x4){0.f, 0.f, 0.f, 0.f};
                c = __builtin_amdgcn_mfma_f32_16x16x32_bf16(kb0, qa0, c, 0, 0, 0);
                c = __builtin_amdgcn_mfma_f32_16x16x32_bf16(kb1, qa1, c, 0, 0, 0);
                cnx[jb] = c;
            }
            __builtin_amdgcn_s_setprio(0);
        }

        // ---- scores of tile t-1 (key_global = k0m + 8g + KBJ[jb] + r)
        if (k0m + 64 <= qw0) {
            const float tbg = c2 * (float)(k0m - qg) + alg;
#pragma unroll
            for (int jb = 0; jb < 4; ++jb) {
                const float tbj = tbg + ckb[jb];
#pragma unroll
                for (int r = 0; r < 4; ++r)
                    p_[jb][r] = fmaf(p_[jb][r], c1, tbj + albr[r] + amv[jb][r]);
            }
        } else if (k0m >= qw0 + 16) {
            const float tbg = c2 * (float)(k0m - qg) + alg;
#pragma unroll
            for (int jb = 0; jb < 4; ++jb) {
                const float tbj = -tbg - ckb[jb];
#pragma unroll
                for (int r = 0; r < 4; ++r)
                    p_[jb][r] = fmaf(p_[jb][r], c1, tbj - albr[r] + amv[jb][r]);
            }
        } else {
            const int dbase = k0m - qg + 8 * g;
#pragma unroll
            for (int jb = 0; jb < 4; ++jb)
#pragma unroll
                for (int r = 0; r < 4; ++r) {
                    int d = dbase + KBJ[jb] + r;
                    d = d < 0 ? -d : d;
                    p_[jb][r] = fmaf(p_[jb][r], c1, amv[jb][r] - c2 * (float)d);
                }
        }

        // ---- row max
        float mx;
        {
            float m0_ = fmaxf(fmaxf(p_[0][0], p_[0][1]), fmaxf(p_[0][2], p_[0][3]));
            float m1_ = fmaxf(fmaxf(p_[1][0], p_[1][1]), fmaxf(p_[1][2], p_[1][3]));
            float m2_ = fmaxf(fmaxf(p_[2][0], p_[2][1]), fmaxf(p_[2][2], p_[2][3]));
            float m3_ = fmaxf(fmaxf(p_[3][0], p_[3][1]), fmaxf(p_[3][2], p_[3][3]));
            mx = fmaxf(fmaxf(m0_, m1_), fmaxf(m2_, m3_));
        }
        mx = fmaxf(mx, __shfl_xor(mx, 16));
        mx = fmaxf(mx, __shfl_xor(mx, 32));

        // ---- defer-max rescale (rare)
        if (__any(mx > m + 8.0f)) {
            const float mn = fmaxf(m, mx);
            const float cr = exp2_(m - mn);
            m = mn;
            l *= cr;
            const int srcb = (lane & 48) + ((lane & 48) >> 2);
#pragma unroll
            for (int r = 0; r < 4; ++r) {
                const float crq = __shfl(cr, srcb + r);
#pragma unroll
                for (int df = 0; df < 4; ++df) Oacc[df][r] *= crq;
            }
        }

        // ---- exp + local sum
        float ps = 0.0f;
#pragma unroll
        for (int jb = 0; jb < 4; ++jb)
#pragma unroll
            for (int r = 0; r < 4; ++r) {
                float p = exp2_(p_[jb][r] - m);
                p_[jb][r] = p;
                ps += p;
            }

        // ---- P-pack: LANE-LOCAL (row-permuted QK^T -> frag order)
        short8 pa0, pa1;
        {
            i32x4 w0 = { (int)cvt_pk_bf16(p_[0][0], p_[0][1]),
                         (int)cvt_pk_bf16(p_[0][2], p_[0][3]),
                         (int)cvt_pk_bf16(p_[1][0], p_[1][1]),
                         (int)cvt_pk_bf16(p_[1][2], p_[1][3]) };
            i32x4 w1 = { (int)cvt_pk_bf16(p_[2][0], p_[2][1]),
                         (int)cvt_pk_bf16(p_[2][2], p_[2][3]),
                         (int)cvt_pk_bf16(p_[3][0], p_[3][1]),
                         (int)cvt_pk_bf16(p_[3][2], p_[3][3]) };
            pa0 = __builtin_bit_cast(short8, w0);
            pa1 = __builtin_bit_cast(short8, w1);
        }

        // ---- PV(t-1): A = P (in-register), B = Vt[vb_r]
        {
            const unsigned short (*Vc)[64] = Vt[vb_r];
            __builtin_amdgcn_s_setprio(1);
#pragma unroll
            for (int df = 0; df < 4; ++df) {
                const char* rowp = (const char*)&Vc[df * 16 + l16][0];
                short8 vb0 = *reinterpret_cast<const short8*>(rowp + vr0Off);
                short8 vb1 = *reinterpret_cast<const short8*>(rowp + vr1Off);
                Oacc[df] = __builtin_amdgcn_mfma_f32_16x16x32_bf16(pa0, vb0, Oacc[df], 0, 0, 0);
                Oacc[df] = __builtin_amdgcn_mfma_f32_16x16x32_bf16(pa1, vb1, Oacc[df], 0, 0, 0);
            }
            __builtin_amdgcn_s_setprio(0);
        }

        // ---- deferred l update
        ps += __shfl_xor(ps, 16);
        ps += __shfl_xor(ps, 32);
        l += ps;

        // ---- stage tile t+1 into LDS (regs loaded last iter), ONE barrier
        if (t + 1 < NT_) {
            *reinterpret_cast<u16x8*>((char*)&Kt[(t + 1) & 1][krow][0] + kwOff) = kr;
#pragma unroll
            for (int j = 0; j < 4; ++j)
                *reinterpret_cast<u16x2*>((char*)&Vt[vb_w][vdb + j][0] + (vkb4 ^ s3x(vdb + j))) =
                    (u16x2){vr0[j], vr1[j]};
            __syncthreads();
            if (t + 2 < NT_) {
                const int kn = (t + 2) * 64;
                kr  = *reinterpret_cast<const u16x8*>(kvb + (size_t)(kn + krow) * N3_ + hk + kgr * 8);
                const unsigned short* vs = kvb + (size_t)(kn + (tid & 31) * 2) * N3_ + hv + vdb;
                vr0 = *reinterpret_cast<const u16x4*>(vs);
                vr1 = *reinterpret_cast<const u16x4*>(vs + N3_);
            }
        }
        vb_r = (vb_r == 2) ? 0 : vb_r + 1;
        vb_w = (vb_w == 2) ? 0 : vb_w + 1;

        // rotate score state
        if (t < NT_) {
#pragma unroll
            for (int jb = 0; jb < 4; ++jb)
#pragma unroll
                for (int r = 0; r < 4; ++r) p_[jb][r] = cnx[jb][r];
        }
    }

    // ---- normalize + store
    const int srcb = (lane & 48) + ((lane & 48) >> 2);
    float invq[4];
#pragma unroll
    for (int r = 0; r < 4; ++r) invq[r] = 1.0f / __shfl(l, srcb + r);
#pragma unroll
    for (int df = 0; df < 4; ++df) {
#pragma unroll
        for (int r = 0; r < 4; ++r) {
            const int qrow = q0 + wq * 16 + g4 + r;
            x[(size_t)(b * S_ + qrow) * D_ + h * 64 + df * 16 + l16] = f2bf(Oacc[df][r] * invq[r]);
        }
    }
}

// ---------------------------------------------------------------------------
extern "C" void kernel_launch(void* const* d_in, const int* in_sizes, int n_in,
                              void* d_out, int out_size, void* d_ws, size_t ws_size,
                              hipStream_t stream) {
    const float* inputs = (const float*)d_in[0];
    const void*  mask   = d_in[1];
    const float* Wqkv   = (const float*)d_in[2];
    const float* bqkv   = (const float*)d_in[3];
    const float* Wproj  = (const float*)d_in[4];
    const float* bproj  = (const float*)d_in[5];
    float* out = (float*)d_out;

    // workspace layout
    unsigned short* qkvb = (unsigned short*)d_ws;         // M*N3 bf16
    unsigned short* xb   = qkvb + (size_t)M_ * N3_;       // M*D  bf16
    unsigned short* Ab   = xb + (size_t)M_ * D_;          // M*D  bf16 (inputs)
    unsigned short* Wqb  = Ab + (size_t)M_ * D_;          // N3*D bf16
    unsigned short* Wpb  = Wqb + (size_t)N3_ * D_;        // D*D  bf16
    float* maskbias = (float*)(Wpb + (size_t)D_ * D_);    // M floats

    k_mask<<<M_ / 256, 256, 0, stream>>>((const unsigned char*)mask, maskbias);

    const int ntot = M_ * D_ + N3_ * D_ + D_ * D_;
    k_f2bf3<<<(ntot / 4 + 255) / 256, 256, 0, stream>>>(inputs, Wqkv, Wproj, Ab, Wqb, Wpb);

    dim3 g1(N3_ / 128, M_ / 128);   // 24 x 32
    k_gemm_bf16_cv<true><<<g1, 512, 0, stream>>>(Ab, Wqb, bqkv, qkvb, M_, N3_, D_);

    k_attn_mfma<<<B_ * H_ * (S_ / 128), 512, 0, stream>>>(qkvb, maskbias, xb);

    dim3 g2(D_ / 128, M_ / 128);    // 8 x 32
    k_gemm_bf16_cv<false><<<g2, 512, 0, stream>>>(xb, Wpb, bproj, out, M_, D_, D_);
}

// Round 20
// 163.643 us; speedup vs baseline: 1.2394x; 1.0097x over previous
//
#include <hip/hip_runtime.h>
#include <cstdint>
#include <cstddef>

// Problem constants (AltAttention: B=2, S=2048, D=1024, H=16, dh=64)
#define B_  2
#define S_  2048
#define D_  1024
#define H_  16
#define DH_ 64
#define M_  (B_*S_)     // 4096 rows
#define N3_ (3*D_)      // 3072 qkv cols
#define NT_ (S_/64)     // 32 key tiles

typedef float f32x4 __attribute__((ext_vector_type(4)));
typedef short short8 __attribute__((ext_vector_type(8)));
typedef int   i32x4 __attribute__((ext_vector_type(4)));
typedef unsigned short u16x8 __attribute__((ext_vector_type(8)));
typedef unsigned short u16x4 __attribute__((ext_vector_type(4)));
typedef unsigned short u16x2 __attribute__((ext_vector_type(2)));

__device__ __forceinline__ unsigned short f2bf(float x) {
    unsigned int u = __float_as_uint(x);
    unsigned int r = (u + 0x7FFFu + ((u >> 16) & 1u)) >> 16;
    return (unsigned short)r;
}

__device__ __forceinline__ float exp2_(float x) { return __builtin_amdgcn_exp2f(x); }

__device__ __forceinline__ unsigned int cvt_pk_bf16(float a, float b) {
    unsigned int r;
    asm volatile("v_cvt_pk_bf16_f32 %0, %1, %2" : "=v"(r) : "v"(a), "v"(b));
    return r;
}

// LDS granule swizzle for attn K/V tiles (verified r17): byte ^= s3(row)<<4.
__device__ __forceinline__ int s3x(int row) {
    return (((row & 3) | (((row >> 3) & 1) << 2)) << 4);
}

// XCD-chunked workgroup swizzle (bijective when nwg % 8 == 0). ATTENTION ONLY.
__device__ __forceinline__ int xcd_swizzle(int lin, int nwg) {
    const int cpx = nwg >> 3;
    return (lin & 7) * cpx + (lin >> 3);
}

__device__ __forceinline__ void gload16(const void* g, void* l) {
    __builtin_amdgcn_global_load_lds(
        (const __attribute__((address_space(1))) unsigned int*)g,
        (__attribute__((address_space(3))) unsigned int*)l,
        16, 0, 0);
}

// ---------------------------------------------------------------------------
// Merged mask detect + expand (verified r16-r19).
// ---------------------------------------------------------------------------
__global__ void k_mask(const unsigned char* __restrict__ mb, float* __restrict__ maskbias) {
    __shared__ int sBig, sM4, sM8;
    if (threadIdx.x == 0) { sBig = 0; sM4 = 0; sM8 = 0; }
    __syncthreads();
    int big = 0, m4 = 0, m8 = 0;
    for (int i = threadIdx.x; i < 4096; i += 256) {
        unsigned char v = mb[i];
        if (v > 1) big = 1;
        if (v && (i & 3)) m4 = 1;
        if (v && ((i & 7) == 4)) m8 = 1;
    }
    if (big) atomicOr(&sBig, 1);
    if (m4)  atomicOr(&sM4, 1);
    if (m8)  atomicOr(&sM8, 1);
    __syncthreads();
    const int w = sBig ? 0 : (sM4 ? 1 : (sM8 ? 4 : 8));
    const int i = blockIdx.x * 256 + threadIdx.x;
    bool on;
    if (w == 0)      on = ((const float*)mb)[i] != 0.0f;
    else if (w == 1) on = mb[i] != 0;
    else if (w == 4) on = ((const int*)mb)[i] != 0;
    else             on = ((const long long*)mb)[i] != 0;
    maskbias[i] = on ? 0.0f : -1e30f;
}

// ---------------------------------------------------------------------------
// Merged fp32 -> bf16 convert (verified r12-r19).
// ---------------------------------------------------------------------------
__global__ void k_f2bf3(const float* __restrict__ A, const float* __restrict__ B2,
                        const float* __restrict__ C, unsigned short* __restrict__ oA,
                        unsigned short* __restrict__ oB, unsigned short* __restrict__ oC) {
    const int nA = M_ * D_, nB = N3_ * D_, nC = D_ * D_;
    int i = (blockIdx.x * 256 + threadIdx.x) * 4;
    const float* src; unsigned short* dst; int off;
    if (i < nA)           { src = A;  dst = oA; off = i; }
    else if (i < nA + nB) { src = B2; dst = oB; off = i - nA; }
    else if (i < nA + nB + nC) { src = C; dst = oC; off = i - nA - nB; }
    else return;
    float4 v = *reinterpret_cast<const float4*>(&src[off]);
    u16x4 o = { f2bf(v.x), f2bf(v.y), f2bf(v.z), f2bf(v.w) };
    *reinterpret_cast<u16x4*>(&dst[off]) = o;
}

// ---------------------------------------------------------------------------
// bf16 MFMA GEMM, counted-vmcnt K-loop + XOR swizzle.
// Round-20: prefetch depth 2 -> 3 (4 LDS buffers, vmcnt(12) steady-state):
// each tile's loads now have TWO compute phases to land (covers ~200cy L2
// latency; depth-2 gave only one ~160cy phase). LDS 128 KiB -> still
// 1 block/CU (unchanged). Same barrier/hazard structure as verified r15.
// ---------------------------------------------------------------------------
template <bool OUT_BF16>
__global__ __launch_bounds__(512) void k_gemm_bf16_cv(
    const unsigned short* __restrict__ A, const unsigned short* __restrict__ W,
    const float* __restrict__ bias, void* __restrict__ Cout,
    int M, int N, int K) {
    __shared__ __align__(16) unsigned short Al[4][128 * 64];
    __shared__ __align__(16) unsigned short Wl[4][128 * 64];

    const int tid  = threadIdx.x;
    const int lane = tid & 63;
    const int w    = tid >> 6;
    const int wr   = w >> 2, wc = w & 3;
    const int l16  = lane & 15, g = lane >> 4;
    const int m0 = blockIdx.y * 128, n0 = blockIdx.x * 128;
    const int NTk = K >> 6;

    f32x4 acc[4][2];
#pragma unroll
    for (int m = 0; m < 4; ++m)
#pragma unroll
        for (int n = 0; n < 2; ++n) acc[m][n] = (f32x4){0.f, 0.f, 0.f, 0.f};

    auto issueTile = [&](int kt) {
        const int k0 = kt << 6;
        unsigned short* Ad = Al[kt & 3];
        unsigned short* Wd = Wl[kt & 3];
#pragma unroll
        for (int i = 0; i < 2; ++i) {
            const int c = i * 512 + tid;
            const int row = c >> 3;
            const int colel = (((c & 7) ^ (row & 7)) << 3);
            gload16(A + (size_t)(m0 + row) * K + k0 + colel, Ad + c * 8);
            gload16(W + (size_t)(n0 + row) * K + k0 + colel, Wd + c * 8);
        }
    };

    issueTile(0);
    issueTile(1);
    issueTile(2);

    for (int t = 0; t < NTk; ++t) {
        if (t + 3 < NTk) issueTile(t + 3);

        // counted waits: tile t landed; up to 3 tiles (12 loads) in flight
        if (t < NTk - 3)       asm volatile("s_waitcnt vmcnt(12)" ::: "memory");
        else if (t == NTk - 3) asm volatile("s_waitcnt vmcnt(8)" ::: "memory");
        else if (t == NTk - 2) asm volatile("s_waitcnt vmcnt(4)" ::: "memory");
        else                   asm volatile("s_waitcnt vmcnt(0)" ::: "memory");
        __builtin_amdgcn_s_barrier();
        __builtin_amdgcn_sched_barrier(0);

        const unsigned short* Ab = Al[t & 3];
        const unsigned short* Wb = Wl[t & 3];
        short8 a[4][2], b[2][2];
#pragma unroll
        for (int m = 0; m < 4; ++m)
#pragma unroll
            for (int kk = 0; kk < 2; ++kk) {
                const int row = wr * 64 + m * 16 + l16;
                const int kb = (kk * 64 + g * 16) ^ ((row & 7) << 4);
                a[m][kk] = *reinterpret_cast<const short8*>(
                    (const char*)Ab + row * 128 + kb);
            }
#pragma unroll
        for (int n = 0; n < 2; ++n)
#pragma unroll
            for (int kk = 0; kk < 2; ++kk) {
                const int row = wc * 32 + n * 16 + l16;
                const int kb = (kk * 64 + g * 16) ^ ((row & 7) << 4);
                b[n][kk] = *reinterpret_cast<const short8*>(
                    (const char*)Wb + row * 128 + kb);
            }

        __builtin_amdgcn_s_setprio(1);
#pragma unroll
        for (int kk = 0; kk < 2; ++kk)
#pragma unroll
            for (int m = 0; m < 4; ++m)
#pragma unroll
                for (int n = 0; n < 2; ++n)
                    acc[m][n] = __builtin_amdgcn_mfma_f32_16x16x32_bf16(
                        a[m][kk], b[n][kk], acc[m][n], 0, 0, 0);
        __builtin_amdgcn_s_setprio(0);

        __builtin_amdgcn_sched_barrier(0);
        __builtin_amdgcn_s_barrier();
    }

    float bv[2];
#pragma unroll
    for (int n = 0; n < 2; ++n) bv[n] = bias[n0 + wc * 32 + n * 16 + l16];
#pragma unroll
    for (int m = 0; m < 4; ++m) {
#pragma unroll
        for (int r = 0; r < 4; ++r) {
            const size_t row = m0 + wr * 64 + m * 16 + g * 4 + r;
#pragma unroll
            for (int n = 0; n < 2; ++n) {
                const int col = n0 + wc * 32 + n * 16 + l16;
                float v = acc[m][n][r] + bv[n];
                if (OUT_BF16)
                    ((unsigned short*)Cout)[row * N + col] = f2bf(v);
                else
                    ((float*)Cout)[row * N + col] = v;
            }
        }
    }
}

// ---------------------------------------------------------------------------
// Flash attention (r17/r19 verbatim — verified 88 us steady-state).
// ---------------------------------------------------------------------------
__global__ __launch_bounds__(512, 4) void k_attn_mfma(
    const unsigned short* __restrict__ qkv,
    const float* __restrict__ maskbias,
    unsigned short* __restrict__ x) {
    __shared__ __align__(16) unsigned short Kt[2][64][64];
    __shared__ __align__(16) unsigned short Vt[3][64][64];

    const int tid  = threadIdx.x;
    const int lane = tid & 63;
    const int wq   = tid >> 6;
    const int g    = lane >> 4;
    const int g4   = g * 4;
    const int l16  = lane & 15;

    const int nqt = S_ / 128;
    const int nwg = B_ * H_ * nqt;
    const int bid = xcd_swizzle(blockIdx.x, nwg);
    const int qt = bid % nqt;
    const int h  = (bid / nqt) % H_;
    const int b  = bid / (nqt * H_);
    const int q0 = qt * 128;
    const size_t rowbase = (size_t)b * S_ * N3_;
    const int hq = h * 192, hk = hq + 64, hv = hq + 128;
    const unsigned short* kvb = qkv + rowbase;
    const float* mbp = maskbias + b * S_;

    const int blrow = 8 * (l16 >> 2) + (l16 & 3);
    const int KBJ[4] = { 0, 4, 32, 36 };

    const unsigned short* qrp = kvb + (size_t)(q0 + wq * 16 + l16) * N3_ + hq;
    const short8 qa0 = *reinterpret_cast<const short8*>(qrp + g * 8);
    const short8 qa1 = *reinterpret_cast<const short8*>(qrp + 32 + g * 8);

    const int krow = tid >> 3;
    const int kgr  = tid & 7;
    const int vkb4 = (tid & 31) * 4;
    const int vdb  = (tid >> 5) * 4;
    u16x8 kr;
    u16x4 vr0, vr1;

    const int kwOff = (kgr << 4) ^ s3x(krow);

    {
        kr  = *reinterpret_cast<const u16x8*>(kvb + (size_t)krow * N3_ + hk + kgr * 8);
        const unsigned short* vs = kvb + (size_t)((tid & 31) * 2) * N3_ + hv + vdb;
        vr0 = *reinterpret_cast<const u16x4*>(vs);
        vr1 = *reinterpret_cast<const u16x4*>(vs + N3_);
        *reinterpret_cast<u16x8*>((char*)&Kt[0][krow][0] + kwOff) = kr;
#pragma unroll
        for (int j = 0; j < 4; ++j)
            *reinterpret_cast<u16x2*>((char*)&Vt[0][vdb + j][0] + (vkb4 ^ s3x(vdb + j))) =
                (u16x2){vr0[j], vr1[j]};
    }
    __syncthreads();

    f32x4 Oacc[4];
#pragma unroll
    for (int df = 0; df < 4; ++df) Oacc[df] = (f32x4){0.f, 0.f, 0.f, 0.f};
    float m = -1e30f, l = 0.0f;

    const float LOG2E = 1.4426950408889634f;
    const float c1 = 0.03125f * LOG2E;
    const float c2 = exp2f(-0.5f * (float)(h + 1)) * LOG2E;
    const int   qw0 = q0 + wq * 16;
    const int   qg  = qw0 + l16;
    const float alg = c2 * (float)(8 * g);
    float albr[4];
#pragma unroll
    for (int r = 0; r < 4; ++r) albr[r] = c2 * (float)r;
    const float ckb[4] = { 0.0f, c2 * 4.0f, c2 * 32.0f, c2 * 36.0f };

    const int sK = s3x(blrow);
    const int kr0Off = (g << 4) ^ sK;
    const int kr1Off = ((4 + g) << 4) ^ sK;
    const int sV = s3x(l16);
    const int vr0Off = (g << 4) ^ sV;
    const int vr1Off = ((4 + g) << 4) ^ sV;

    float p_[4][4];

    {
        kr  = *reinterpret_cast<const u16x8*>(kvb + (size_t)(64 + krow) * N3_ + hk + kgr * 8);
        const unsigned short* vs = kvb + (size_t)(64 + (tid & 31) * 2) * N3_ + hv + vdb;
        vr0 = *reinterpret_cast<const u16x4*>(vs);
        vr1 = *reinterpret_cast<const u16x4*>(vs + N3_);

        __builtin_amdgcn_s_setprio(1);
#pragma unroll
        for (int jb = 0; jb < 4; ++jb) {
            const char* rowp = (const char*)&Kt[0][blrow + KBJ[jb]][0];
            short8 kb0 = *reinterpret_cast<const short8*>(rowp + kr0Off);
            short8 kb1 = *reinterpret_cast<const short8*>(rowp + kr1Off);
            f32x4 c = (f32x4){0.f, 0.f, 0.f, 0.f};
            c = __builtin_amdgcn_mfma_f32_16x16x32_bf16(kb0, qa0, c, 0, 0, 0);
            c = __builtin_amdgcn_mfma_f32_16x16x32_bf16(kb1, qa1, c, 0, 0, 0);
#pragma unroll
            for (int r = 0; r < 4; ++r) p_[jb][r] = c[r];
        }
        __builtin_amdgcn_s_setprio(0);

        *reinterpret_cast<u16x8*>((char*)&Kt[1][krow][0] + kwOff) = kr;
#pragma unroll
        for (int j = 0; j < 4; ++j)
            *reinterpret_cast<u16x2*>((char*)&Vt[1][vdb + j][0] + (vkb4 ^ s3x(vdb + j))) =
                (u16x2){vr0[j], vr1[j]};
    }
    __syncthreads();
    {
        kr  = *reinterpret_cast<const u16x8*>(kvb + (size_t)(128 + krow) * N3_ + hk + kgr * 8);
        const unsigned short* vs = kvb + (size_t)(128 + (tid & 31) * 2) * N3_ + hv + vdb;
        vr0 = *reinterpret_cast<const u16x4*>(vs);
        vr1 = *reinterpret_cast<const u16x4*>(vs + N3_);
    }

    int vb_r = 0;
    int vb_w = 2;

    for (int t = 1; t < NT_ + 1; ++t) {
        const int k0m = (t - 1) * 64;

        f32x4 amv[4];
#pragma unroll
        for (int jb = 0; jb < 4; ++jb)
            amv[jb] = *reinterpret_cast<const f32x4*>(&mbp[k0m + 8 * g + KBJ[jb]]);

        f32x4 cnx[4];
        if (t < NT_) {
            const unsigned short (*Kc)[64] = Kt[t & 1];
            __builtin_amdgcn_s_setprio(1);
#pragma unroll
            for (int jb = 0; jb < 4; ++jb) {
                const char* rowp = (const char*)&Kc[blrow + KBJ[jb]][0];
                short8 kb0 = *reinterpret_cast<const short8*>(rowp + kr0Off);
                short8 kb1 = *reinterpret_cast<const short8*>(rowp + kr1Off);
                f32x4 c = (f32x4){0.f, 0.f, 0.f, 0.f};
                c = __builtin_amdgcn_mfma_f32_16x16x32_bf16(kb0, qa0, c, 0, 0, 0);
                c = __builtin_amdgcn_mfma_f32_16x16x32_bf16(kb1, qa1, c, 0, 0, 0);
                cnx[jb] = c;
            }
            __builtin_amdgcn_s_setprio(0);
        }

        if (k0m + 64 <= qw0) {
            const float tbg = c2 * (float)(k0m - qg) + alg;
#pragma unroll
            for (int jb = 0; jb < 4; ++jb) {
                const float tbj = tbg + ckb[jb];
#pragma unroll
                for (int r = 0; r < 4; ++r)
                    p_[jb][r] = fmaf(p_[jb][r], c1, tbj + albr[r] + amv[jb][r]);
            }
        } else if (k0m >= qw0 + 16) {
            const float tbg = c2 * (float)(k0m - qg) + alg;
#pragma unroll
            for (int jb = 0; jb < 4; ++jb) {
                const float tbj = -tbg - ckb[jb];
#pragma unroll
                for (int r = 0; r < 4; ++r)
                    p_[jb][r] = fmaf(p_[jb][r], c1, tbj - albr[r] + amv[jb][r]);
            }
        } else {
            const int dbase = k0m - qg + 8 * g;
#pragma unroll
            for (int jb = 0; jb < 4; ++jb)
#pragma unroll
                for (int r = 0; r < 4; ++r) {
                    int d = dbase + KBJ[jb] + r;
                    d = d < 0 ? -d : d;
                    p_[jb][r] = fmaf(p_[jb][r], c1, amv[jb][r] - c2 * (float)d);
                }
        }

        float mx;
        {
            float m0_ = fmaxf(fmaxf(p_[0][0], p_[0][1]), fmaxf(p_[0][2], p_[0][3]));
            float m1_ = fmaxf(fmaxf(p_[1][0], p_[1][1]), fmaxf(p_[1][2], p_[1][3]));
            float m2_ = fmaxf(fmaxf(p_[2][0], p_[2][1]), fmaxf(p_[2][2], p_[2][3]));
            float m3_ = fmaxf(fmaxf(p_[3][0], p_[3][1]), fmaxf(p_[3][2], p_[3][3]));
            mx = fmaxf(fmaxf(m0_, m1_), fmaxf(m2_, m3_));
        }
        mx = fmaxf(mx, __shfl_xor(mx, 16));
        mx = fmaxf(mx, __shfl_xor(mx, 32));

        if (__any(mx > m + 8.0f)) {
            const float mn = fmaxf(m, mx);
            const float cr = exp2_(m - mn);
            m = mn;
            l *= cr;
            const int srcb = (lane & 48) + ((lane & 48) >> 2);
#pragma unroll
            for (int r = 0; r < 4; ++r) {
                const float crq = __shfl(cr, srcb + r);
#pragma unroll
                for (int df = 0; df < 4; ++df) Oacc[df][r] *= crq;
            }
        }

        float ps = 0.0f;
#pragma unroll
        for (int jb = 0; jb < 4; ++jb)
#pragma unroll
            for (int r = 0; r < 4; ++r) {
                float p = exp2_(p_[jb][r] - m);
                p_[jb][r] = p;
                ps += p;
            }

        short8 pa0, pa1;
        {
            i32x4 w0 = { (int)cvt_pk_bf16(p_[0][0], p_[0][1]),
                         (int)cvt_pk_bf16(p_[0][2], p_[0][3]),
                         (int)cvt_pk_bf16(p_[1][0], p_[1][1]),
                         (int)cvt_pk_bf16(p_[1][2], p_[1][3]) };
            i32x4 w1 = { (int)cvt_pk_bf16(p_[2][0], p_[2][1]),
                         (int)cvt_pk_bf16(p_[2][2], p_[2][3]),
                         (int)cvt_pk_bf16(p_[3][0], p_[3][1]),
                         (int)cvt_pk_bf16(p_[3][2], p_[3][3]) };
            pa0 = __builtin_bit_cast(short8, w0);
            pa1 = __builtin_bit_cast(short8, w1);
        }

        {
            const unsigned short (*Vc)[64] = Vt[vb_r];
            __builtin_amdgcn_s_setprio(1);
#pragma unroll
            for (int df = 0; df < 4; ++df) {
                const char* rowp = (const char*)&Vc[df * 16 + l16][0];
                short8 vb0 = *reinterpret_cast<const short8*>(rowp + vr0Off);
                short8 vb1 = *reinterpret_cast<const short8*>(rowp + vr1Off);
                Oacc[df] = __builtin_amdgcn_mfma_f32_16x16x32_bf16(pa0, vb0, Oacc[df], 0, 0, 0);
                Oacc[df] = __builtin_amdgcn_mfma_f32_16x16x32_bf16(pa1, vb1, Oacc[df], 0, 0, 0);
            }
            __builtin_amdgcn_s_setprio(0);
        }

        ps += __shfl_xor(ps, 16);
        ps += __shfl_xor(ps, 32);
        l += ps;

        if (t + 1 < NT_) {
            *reinterpret_cast<u16x8*>((char*)&Kt[(t + 1) & 1][krow][0] + kwOff) = kr;
#pragma unroll
            for (int j = 0; j < 4; ++j)
                *reinterpret_cast<u16x2*>((char*)&Vt[vb_w][vdb + j][0] + (vkb4 ^ s3x(vdb + j))) =
                    (u16x2){vr0[j], vr1[j]};
            __syncthreads();
            if (t + 2 < NT_) {
                const int kn = (t + 2) * 64;
                kr  = *reinterpret_cast<const u16x8*>(kvb + (size_t)(kn + krow) * N3_ + hk + kgr * 8);
                const unsigned short* vs = kvb + (size_t)(kn + (tid & 31) * 2) * N3_ + hv + vdb;
                vr0 = *reinterpret_cast<const u16x4*>(vs);
                vr1 = *reinterpret_cast<const u16x4*>(vs + N3_);
            }
        }
        vb_r = (vb_r == 2) ? 0 : vb_r + 1;
        vb_w = (vb_w == 2) ? 0 : vb_w + 1;

        if (t < NT_) {
#pragma unroll
            for (int jb = 0; jb < 4; ++jb)
#pragma unroll
                for (int r = 0; r < 4; ++r) p_[jb][r] = cnx[jb][r];
        }
    }

    const int srcb = (lane & 48) + ((lane & 48) >> 2);
    float invq[4];
#pragma unroll
    for (int r = 0; r < 4; ++r) invq[r] = 1.0f / __shfl(l, srcb + r);
#pragma unroll
    for (int df = 0; df < 4; ++df) {
#pragma unroll
        for (int r = 0; r < 4; ++r) {
            const int qrow = q0 + wq * 16 + g4 + r;
            x[(size_t)(b * S_ + qrow) * D_ + h * 64 + df * 16 + l16] = f2bf(Oacc[df][r] * invq[r]);
        }
    }
}

// ---------------------------------------------------------------------------
extern "C" void kernel_launch(void* const* d_in, const int* in_sizes, int n_in,
                              void* d_out, int out_size, void* d_ws, size_t ws_size,
                              hipStream_t stream) {
    const float* inputs = (const float*)d_in[0];
    const void*  mask   = d_in[1];
    const float* Wqkv   = (const float*)d_in[2];
    const float* bqkv   = (const float*)d_in[3];
    const float* Wproj  = (const float*)d_in[4];
    const float* bproj  = (const float*)d_in[5];
    float* out = (float*)d_out;

    // workspace layout
    unsigned short* qkvb = (unsigned short*)d_ws;         // M*N3 bf16
    unsigned short* xb   = qkvb + (size_t)M_ * N3_;       // M*D  bf16
    unsigned short* Ab   = xb + (size_t)M_ * D_;          // M*D  bf16 (inputs)
    unsigned short* Wqb  = Ab + (size_t)M_ * D_;          // N3*D bf16
    unsigned short* Wpb  = Wqb + (size_t)N3_ * D_;        // D*D  bf16
    float* maskbias = (float*)(Wpb + (size_t)D_ * D_);    // M floats

    k_mask<<<M_ / 256, 256, 0, stream>>>((const unsigned char*)mask, maskbias);

    const int ntot = M_ * D_ + N3_ * D_ + D_ * D_;
    k_f2bf3<<<(ntot / 4 + 255) / 256, 256, 0, stream>>>(inputs, Wqkv, Wproj, Ab, Wqb, Wpb);

    dim3 g1(N3_ / 128, M_ / 128);   // 24 x 32
    k_gemm_bf16_cv<true><<<g1, 512, 0, stream>>>(Ab, Wqb, bqkv, qkvb, M_, N3_, D_);

    k_attn_mfma<<<B_ * H_ * (S_ / 128), 512, 0, stream>>>(qkvb, maskbias, xb);

    dim3 g2(D_ / 128, M_ / 128);    // 8 x 32
    k_gemm_bf16_cv<false><<<g2, 512, 0, stream>>>(xb, Wpb, bproj, out, M_, D_, D_);
}